// Round 3
// baseline (690.329 us; speedup 1.0000x reference)
//
#include <hip/hip_runtime.h>

#define BB 32
#define SS 4096
#define HH 1024
#define BS (BB * SS)            // 131072 rows
#define NW 16384                // waves in k_proj
#define NBLK (NW / 4)           // 4096 blocks of 256
#define RPW (BS / NW)           // 8 rows per wave

// Order-preserving float -> uint key (unsigned compare == float compare)
__device__ __forceinline__ unsigned fkey(float f) {
    unsigned u = __float_as_uint(f);
    return (u & 0x80000000u) ? ~u : (u | 0x80000000u);
}
__device__ __forceinline__ float funkey(unsigned k) {
    unsigned u = (k & 0x80000000u) ? (k ^ 0x80000000u) : ~k;
    return __uint_as_float(u);
}
__device__ __forceinline__ float dot4(float4 a, float4 w) {
    return a.x * w.x + a.y * w.y + a.z * w.z + a.w * w.w;
}

// v4: persistent-wave streaming GEMV.
//  - 4096 blocks (16 blocks/CU queue) -> no one-shot block churn (v3's limiter)
//  - loop body is ONLY {prefetch next row, dot, butterfly, store}: the in-loop
//    mask load / minmax chain that serialized v1 lives in k_minmax instead
//  - full unroll: rotation moves vanish by renaming; 128-VGPR cap from
//    __launch_bounds__(256,4) bounds the compiler's load-hoist depth to a
//    3-4 row pipeline (v2's 16-deep hoist blew the register file)
__global__ __launch_bounds__(256, 4) void k_proj(
    const float* __restrict__ x, const float* __restrict__ W,
    const float* __restrict__ bvec, float* __restrict__ h)
{
    const int lane = threadIdx.x & 63;
    const int gw   = blockIdx.x * 4 + (threadIdx.x >> 6);   // 0..NW-1

    const float4* Wv = (const float4*)W;                    // 4 KB, L1/L2-hot
    const float4 w0 = Wv[lane],       w1 = Wv[64 + lane],
                 w2 = Wv[128 + lane], w3 = Wv[192 + lane];
    const float bval = bvec[0];

    // rows for this wave: gw + k*NW, k = 0..RPW-1 (consecutive waves ->
    // consecutive 4 KB rows -> fully coalesced chip-wide)
    const float4* xr = (const float4*)(x + (size_t)gw * HH);
    float4 a0 = xr[lane],       a1 = xr[64 + lane],
           a2 = xr[128 + lane], a3 = xr[192 + lane];

#pragma unroll
    for (int k = 0; k < RPW; ++k) {
        float4 b0, b1, b2, b3;
        if (k < RPW - 1) {   // issue next row's loads before this row's reduce
            const float4* xn = (const float4*)(x + ((size_t)gw + (size_t)(k + 1) * NW) * HH);
            b0 = xn[lane]; b1 = xn[64 + lane]; b2 = xn[128 + lane]; b3 = xn[192 + lane];
        }
        float acc = dot4(a0, w0) + dot4(a1, w1) + dot4(a2, w2) + dot4(a3, w3);
#pragma unroll
        for (int off = 32; off >= 1; off >>= 1)
            acc += __shfl_xor(acc, off, 64);
        if (lane == 0) h[(size_t)gw + (size_t)k * NW] = acc + bval;
        a0 = b0; a1 = b1; a2 = b2; a3 = b3;
    }
}

// Per-batch masked min/max over h (1 MB total input) -> mm[64].
// Unconditional writes: no init memsets, no atomics.
__global__ __launch_bounds__(256) void k_minmax(
    const float* __restrict__ h, const int* __restrict__ mask,
    unsigned* __restrict__ mm)
{
    const int batch = blockIdx.x;            // 32 blocks
    const int t = threadIdx.x;
    const size_t base = (size_t)batch * SS;

    unsigned kmin = 0xFFFFFFFFu, kmax = 0u;
    for (int i = t; i < SS; i += 256) {
        if (mask[base + i] != 0) {
            const unsigned k = fkey(h[base + i]);
            kmin = min(kmin, k); kmax = max(kmax, k);
        }
    }
#pragma unroll
    for (int off = 32; off >= 1; off >>= 1) {
        kmin = min(kmin, (unsigned)__shfl_xor((int)kmin, off, 64));
        kmax = max(kmax, (unsigned)__shfl_xor((int)kmax, off, 64));
    }
    __shared__ unsigned smin[4], smax[4];
    if ((t & 63) == 0) { smin[t >> 6] = kmin; smax[t >> 6] = kmax; }
    __syncthreads();
    if (t == 0) {
        const unsigned m0 = min(min(smin[0], smin[1]), min(smin[2], smin[3]));
        const unsigned M0 = max(max(smax[0], smax[1]), max(smax[2], smax[3]));
        mm[batch] = m0; mm[BB + batch] = M0;
    }
}

// out = mask ? (h - hmin)/(hmax - hmin) : 0   (mean/std cancel algebraically)
__global__ __launch_bounds__(256) void k_final(
    const float* __restrict__ h, const int* __restrict__ mask,
    const unsigned* __restrict__ mm, float* __restrict__ out)
{
    const int i = blockIdx.x * 256 + threadIdx.x;
    if (i >= BS) return;
    const int batch = i >> 12;
    const float hmin = funkey(mm[batch]);
    const float hmax = funkey(mm[BB + batch]);
    const float inv = 1.0f / (hmax - hmin);
    const float v = (h[i] - hmin) * inv;
    out[i] = (mask[i] != 0) ? v : 0.0f;
}

extern "C" void kernel_launch(void* const* d_in, const int* in_sizes, int n_in,
                              void* d_out, int out_size, void* d_ws, size_t ws_size,
                              hipStream_t stream) {
    const float* x    = (const float*)d_in[0];
    const int*   mask = (const int*)d_in[1];
    const float* W    = (const float*)d_in[2];
    const float* bv   = (const float*)d_in[3];
    float* out = (float*)d_out;

    float*    h  = (float*)d_ws;                                   // BS floats
    unsigned* mm = (unsigned*)((char*)d_ws + (size_t)BS * 4);      // 2*BB uints

    k_proj<<<NBLK, 256, 0, stream>>>(x, W, bv, h);
    k_minmax<<<BB, 256, 0, stream>>>(h, mask, mm);
    k_final<<<(BS + 255) / 256, 256, 0, stream>>>(h, mask, mm, out);
}